// Round 1
// baseline (2974.366 us; speedup 1.0000x reference)
//
#include <hip/hip_runtime.h>
#include <hip/hip_bf16.h>
#include <math.h>

#define ND 768
#define NNODES 50000
#define NEDGES 100000
#define NPAD 50048  // 391 * 128, so the GEMM M-dim needs no edge guards

using bf16x8 = __attribute__((ext_vector_type(8))) __bf16;
using f32x4  = __attribute__((ext_vector_type(4))) float;

__device__ __forceinline__ unsigned short f2b(float f) {
  union { float f; unsigned u; } x; x.f = f;
  unsigned r = x.u + 0x7fffu + ((x.u >> 16) & 1u);  // round-to-nearest-even
  return (unsigned short)(r >> 16);
}
__device__ __forceinline__ float b2f(unsigned short h) {
  union { unsigned u; float f; } x; x.u = ((unsigned)h) << 16;
  return x.f;
}

// ---------------- weight prep: transpose + bf16 convert ----------------
// wt[j][k] = W[k][j] so that A and B^T MFMA fragments use identical loads.
__global__ __launch_bounds__(256) void prep_wt_k(
    const float* __restrict__ gcn_w, const float* __restrict__ gate_w,
    unsigned short* __restrict__ wt0, unsigned short* __restrict__ wt1,
    unsigned short* __restrict__ gwt) {
  int idx = blockIdx.x * 256 + threadIdx.x;  // 3 * 768 * 768 total
  int m = idx / (ND * ND);
  int r = idx % (ND * ND);
  int j = r / ND, k = r % ND;
  float v;
  if (m == 0)      v = gcn_w[k * ND + j];
  else if (m == 1) v = gcn_w[ND * ND + k * ND + j];
  else             v = gate_w[k * ND + j];  // top half of gate_w
  unsigned short* o = (m == 0) ? wt0 : (m == 1) ? wt1 : gwt;
  o[r] = f2b(v);
}

// aspect_proj[j] = sum_k aspect[k] * gate_w[D + k][j] + gate_b[j]  (layer-invariant)
__global__ __launch_bounds__(256) void prep_aspect_k(
    const float* __restrict__ aspect, const float* __restrict__ gate_w,
    const float* __restrict__ gate_b, float* __restrict__ out) {
  int j = blockIdx.x * 256 + threadIdx.x;
  if (j >= ND) return;
  float s = gate_b[j];
  for (int k = 0; k < ND; ++k) s += aspect[k] * gate_w[(ND + k) * ND + j];
  out[j] = s;
}

// ---------------- scatter-add aggregation ----------------
__global__ __launch_bounds__(256) void scatter_add_k(
    const float* __restrict__ x, const int* __restrict__ src,
    const int* __restrict__ dst, float* __restrict__ agg) {
  int idx = blockIdx.x * 256 + threadIdx.x;  // E * 192 threads
  int e = idx / 192;
  if (e >= NEDGES) return;
  int t = (idx % 192) * 4;
  int s = src[e], d = dst[e];
  const float4 v = *reinterpret_cast<const float4*>(x + (size_t)s * ND + t);
  float* p = agg + (size_t)d * ND + t;
#if defined(__has_builtin) && __has_builtin(__builtin_amdgcn_global_atomic_fadd_f32)
  unsafeAtomicAdd(p + 0, v.x);
  unsafeAtomicAdd(p + 1, v.y);
  unsafeAtomicAdd(p + 2, v.z);
  unsafeAtomicAdd(p + 3, v.w);
#else
  atomicAdd(p + 0, v.x); atomicAdd(p + 1, v.y);
  atomicAdd(p + 2, v.z); atomicAdd(p + 3, v.w);
#endif
}

// ---------------- f32 -> bf16 conversion ----------------
__global__ __launch_bounds__(256) void f32_to_bf16_k(
    const float* __restrict__ in, unsigned short* __restrict__ out, int n4) {
  int i = blockIdx.x * 256 + threadIdx.x;
  if (i >= n4) return;
  float4 v = reinterpret_cast<const float4*>(in)[i];
  ushort4 o;
  o.x = f2b(v.x); o.y = f2b(v.y); o.z = f2b(v.z); o.w = f2b(v.w);
  reinterpret_cast<ushort4*>(out)[i] = o;
}

// ---------------- bf16 GEMM, C = A[M,K] x Bt[N,K]^T, m97 structure ----------------
// epi 0: out_bf16 = relu(acc + bias[col])          (x_gcn)
// epi 1: out_bf16 = sigmoid(acc + bias[col])       (gate)
__global__ __launch_bounds__(256) void gemm_bt_k(
    const unsigned short* __restrict__ A,   // [NPAD][768] bf16
    const unsigned short* __restrict__ Bt,  // [768][768] bf16 (transposed weights)
    const float* __restrict__ bias,         // [768]
    unsigned short* __restrict__ outb,      // [NPAD][768] bf16
    int epi) {
  __shared__ __align__(16) unsigned short lA[128 * 32];
  __shared__ __align__(16) unsigned short lB[128 * 32];
  const int tid = threadIdx.x;
  const int lane = tid & 63;
  const int wid = tid >> 6;
  const int brow = blockIdx.x / 6;
  const int bcol = blockIdx.x % 6;
  const int wr = wid >> 1, wc = wid & 1;  // 2x2 waves of 64x64

  f32x4 acc[4][4] = {};
  const int lr = lane & 15;
  const int ks = (lane >> 4) * 8;

  for (int k0 = 0; k0 < ND; k0 += 32) {
    // stage 128x32 A and B tiles via global_load_lds (16B/lane)
#pragma unroll
    for (int it = 0; it < 2; ++it) {
      int lid = it * 256 + tid;
      int r = lid >> 2;
      int c = (lid & 3) * 8;
      const unsigned short* ga = A + (size_t)(brow * 128 + r) * ND + k0 + c;
      const unsigned short* gb = Bt + (size_t)(bcol * 128 + r) * ND + k0 + c;
      unsigned short* la = &lA[(size_t)(it * 256 + wid * 64) * 8];
      unsigned short* lb = &lB[(size_t)(it * 256 + wid * 64) * 8];
      __builtin_amdgcn_global_load_lds(
          (const __attribute__((address_space(1))) char*)ga,
          (__attribute__((address_space(3))) char*)la, 16, 0, 0);
      __builtin_amdgcn_global_load_lds(
          (const __attribute__((address_space(1))) char*)gb,
          (__attribute__((address_space(3))) char*)lb, 16, 0, 0);
    }
    __syncthreads();
    bf16x8 a[4], b[4];
#pragma unroll
    for (int mi = 0; mi < 4; ++mi)
      a[mi] = *reinterpret_cast<const bf16x8*>(&lA[(wr * 64 + mi * 16 + lr) * 32 + ks]);
#pragma unroll
    for (int ni = 0; ni < 4; ++ni)
      b[ni] = *reinterpret_cast<const bf16x8*>(&lB[(wc * 64 + ni * 16 + lr) * 32 + ks]);
#pragma unroll
    for (int mi = 0; mi < 4; ++mi)
#pragma unroll
      for (int ni = 0; ni < 4; ++ni)
        acc[mi][ni] = __builtin_amdgcn_mfma_f32_16x16x32_bf16(a[mi], b[ni], acc[mi][ni], 0, 0, 0);
    __syncthreads();
  }

  // epilogue: C/D layout col = lane&15, row = (lane>>4)*4 + reg  [m89-verified]
#pragma unroll
  for (int ni = 0; ni < 4; ++ni) {
    int col = bcol * 128 + wc * 64 + ni * 16 + lr;
    float bj = bias[col];
#pragma unroll
    for (int mi = 0; mi < 4; ++mi) {
      int row0 = brow * 128 + wr * 64 + mi * 16 + (lane >> 4) * 4;
#pragma unroll
      for (int r = 0; r < 4; ++r) {
        float v = acc[mi][ni][r] + bj;
        if (epi == 0) v = fmaxf(v, 0.f);
        else          v = 1.f / (1.f + __expf(-v));
        outb[(size_t)(row0 + r) * ND + col] = f2b(v);
      }
    }
  }
}

// ---------------- gate combine + LayerNorm (fused, one block per row) ----------------
__global__ __launch_bounds__(256) void combine_ln_k(
    const unsigned short* __restrict__ gate, const unsigned short* __restrict__ xgcn,
    const float* __restrict__ xin, const float* __restrict__ gamma,
    const float* __restrict__ beta, float* __restrict__ out) {
  int row = blockIdx.x;
  int tid = threadIdx.x;
  int lane = tid & 63, wid = tid >> 6;
  size_t base = (size_t)row * ND;
  float v[3];
  float s = 0.f, s2 = 0.f;
#pragma unroll
  for (int i = 0; i < 3; ++i) {
    int c = tid + i * 256;
    float g  = b2f(gate[base + c]);
    float xg = b2f(xgcn[base + c]);
    float xo = xin[base + c];
    float val = g * xg + (1.f - g) * xo;
    v[i] = val; s += val; s2 += val * val;
  }
#pragma unroll
  for (int o = 1; o < 64; o <<= 1) { s += __shfl_xor(s, o); s2 += __shfl_xor(s2, o); }
  __shared__ float red[2][4];
  if (lane == 0) { red[0][wid] = s; red[1][wid] = s2; }
  __syncthreads();
  s  = red[0][0] + red[0][1] + red[0][2] + red[0][3];
  s2 = red[1][0] + red[1][1] + red[1][2] + red[1][3];
  float mu  = s * (1.f / ND);
  float var = s2 * (1.f / ND) - mu * mu;
  float inv = rsqrtf(var + 1e-5f);
#pragma unroll
  for (int i = 0; i < 3; ++i) {
    int c = tid + i * 256;
    out[base + c] = (v[i] - mu) * inv * gamma[c] + beta[c];
  }
}

// ---------------- launch ----------------
extern "C" void kernel_launch(void* const* d_in, const int* in_sizes, int n_in,
                              void* d_out, int out_size, void* d_ws, size_t ws_size,
                              hipStream_t stream) {
  const float* token  = (const float*)d_in[0];
  const int*   eidx   = (const int*)d_in[1];
  const float* aspect = (const float*)d_in[2];
  const float* gcn_w  = (const float*)d_in[3];
  const float* gcn_b  = (const float*)d_in[4];
  const float* gate_w = (const float*)d_in[5];
  const float* gate_b = (const float*)d_in[6];
  const float* ln_g   = (const float*)d_in[7];
  const float* ln_b   = (const float*)d_in[8];
  float* out = (float*)d_out;

  const int* src = eidx;
  const int* dst = eidx + NEDGES;

  char* ws = (char*)d_ws;
  size_t off = 0;
  float* agg = (float*)(ws + off);                 off += (size_t)NPAD * ND * 4;
  unsigned short* aggb = (unsigned short*)(ws + off); off += (size_t)NPAD * ND * 2;
  unsigned short* xgcn = (unsigned short*)(ws + off); off += (size_t)NPAD * ND * 2;
  unsigned short* wt0  = (unsigned short*)(ws + off); off += (size_t)ND * ND * 2;
  unsigned short* wt1  = (unsigned short*)(ws + off); off += (size_t)ND * ND * 2;
  unsigned short* gwt  = (unsigned short*)(ws + off); off += (size_t)ND * ND * 2;
  float* aproj = (float*)(ws + off);               off += ND * 4;
  unsigned short* gateb = (unsigned short*)agg;  // agg is dead once gate GEMM runs

  hipLaunchKernelGGL(prep_wt_k, dim3((3 * ND * ND) / 256), dim3(256), 0, stream,
                     gcn_w, gate_w, wt0, wt1, gwt);
  hipLaunchKernelGGL(prep_aspect_k, dim3(3), dim3(256), 0, stream,
                     aspect, gate_w, gate_b, aproj);

  const int n4 = NPAD * ND / 4;
  for (int l = 0; l < 2; ++l) {
    const float* xin = (l == 0) ? token : out;
    hipMemsetAsync(agg, 0, (size_t)NPAD * ND * 4, stream);
    hipLaunchKernelGGL(scatter_add_k, dim3((NEDGES * 192) / 256), dim3(256), 0, stream,
                       xin, src, dst, agg);
    hipLaunchKernelGGL(f32_to_bf16_k, dim3((n4 + 255) / 256), dim3(256), 0, stream,
                       agg, aggb, n4);
    hipLaunchKernelGGL(gemm_bt_k, dim3(391 * 6), dim3(256), 0, stream,
                       aggb, (l == 0) ? wt0 : wt1, gcn_b + l * ND, xgcn, 0);
    hipLaunchKernelGGL(gemm_bt_k, dim3(391 * 6), dim3(256), 0, stream,
                       xgcn, gwt, aproj, gateb, 1);
    hipLaunchKernelGGL(combine_ln_k, dim3(NNODES), dim3(256), 0, stream,
                       gateb, xgcn, xin, ln_g + l * ND, ln_b + l * ND, out);
  }
}

// Round 6
// 1004.312 us; speedup vs baseline: 2.9616x; 2.9616x over previous
//
#include <hip/hip_runtime.h>
#include <hip/hip_bf16.h>
#include <math.h>

#define ND 768
#define NNODES 50000
#define NEDGES 100000
#define NPAD 50048            // 391 * 128: GEMM M-dim needs no edge guards
#define NSB ((NNODES + 255) / 256)   // 196 scan blocks

using bf16x8 = __attribute__((ext_vector_type(8))) __bf16;
using f32x4  = __attribute__((ext_vector_type(4))) float;

__device__ __forceinline__ unsigned short f2b(float f) {
  union { float f; unsigned u; } x; x.f = f;
  unsigned r = x.u + 0x7fffu + ((x.u >> 16) & 1u);  // RNE
  return (unsigned short)(r >> 16);
}
__device__ __forceinline__ float b2f(unsigned short h) {
  union { unsigned u; float f; } x; x.u = ((unsigned)h) << 16;
  return x.f;
}
__device__ __forceinline__ int wave_incl_scan(int v, int lane) {
#pragma unroll
  for (int o = 1; o < 64; o <<= 1) { int t = __shfl_up(v, o); if (lane >= o) v += t; }
  return v;
}

// ---------------- weight prep: transpose + bf16 convert ----------------
__global__ __launch_bounds__(256) void prep_wt_k(
    const float* __restrict__ gcn_w, const float* __restrict__ gate_w,
    unsigned short* __restrict__ wt0, unsigned short* __restrict__ wt1,
    unsigned short* __restrict__ gwt) {
  int idx = blockIdx.x * 256 + threadIdx.x;  // 3 * 768 * 768 total
  int m = idx / (ND * ND);
  int r = idx % (ND * ND);
  int j = r / ND, k = r % ND;
  float v;
  if (m == 0)      v = gcn_w[k * ND + j];
  else if (m == 1) v = gcn_w[ND * ND + k * ND + j];
  else             v = gate_w[k * ND + j];
  unsigned short* o = (m == 0) ? wt0 : (m == 1) ? wt1 : gwt;
  o[r] = f2b(v);
}

// aspect_proj[j] = sum_k aspect[k] * gate_w[D + k][j] + gate_b[j]
__global__ __launch_bounds__(256) void prep_aspect_k(
    const float* __restrict__ aspect, const float* __restrict__ gate_w,
    const float* __restrict__ gate_b, float* __restrict__ out) {
  int j = blockIdx.x * 256 + threadIdx.x;
  if (j >= ND) return;
  float s = gate_b[j];
  for (int k = 0; k < ND; ++k) s += aspect[k] * gate_w[(ND + k) * ND + j];
  out[j] = s;
}

// ---------------- CSR build ----------------
__global__ __launch_bounds__(256) void hist_k(const int* __restrict__ dst, int* __restrict__ cnt) {
  int e = blockIdx.x * 256 + threadIdx.x;
  if (e < NEDGES) atomicAdd(&cnt[dst[e]], 1);
}

// per-block sums of cnt
__global__ __launch_bounds__(256) void scan1_k(const int* __restrict__ cnt, int* __restrict__ bsum) {
  int i = blockIdx.x * 256 + threadIdx.x;
  int lane = threadIdx.x & 63, wid = threadIdx.x >> 6;
  int v = (i < NNODES) ? cnt[i] : 0;
#pragma unroll
  for (int o = 1; o < 64; o <<= 1) v += __shfl_xor(v, o);
  __shared__ int ws[4];
  if (lane == 0) ws[wid] = v;
  __syncthreads();
  if (threadIdx.x == 0) bsum[blockIdx.x] = ws[0] + ws[1] + ws[2] + ws[3];
}

// exclusive scan of the 196 block sums (single block)
__global__ __launch_bounds__(256) void scan2_k(const int* __restrict__ bsum, int* __restrict__ boff) {
  int tid = threadIdx.x, lane = tid & 63, wid = tid >> 6;
  int v = (tid < NSB) ? bsum[tid] : 0;
  int incl = wave_incl_scan(v, lane);
  __shared__ int ws[4];
  if (lane == 63) ws[wid] = incl;
  __syncthreads();
  int add = 0;
  for (int w = 0; w < wid; ++w) add += ws[w];
  if (tid < NSB) boff[tid] = incl - v + add;
}

// per-block exclusive rescan + global offset -> row_ptr & cursor
__global__ __launch_bounds__(256) void scan3_k(
    const int* __restrict__ cnt, const int* __restrict__ boff,
    int* __restrict__ row_ptr, int* __restrict__ cursor) {
  int i = blockIdx.x * 256 + threadIdx.x;
  int tid = threadIdx.x, lane = tid & 63, wid = tid >> 6;
  int v = (i < NNODES) ? cnt[i] : 0;
  int incl = wave_incl_scan(v, lane);
  __shared__ int ws[4];
  if (lane == 63) ws[wid] = incl;
  __syncthreads();
  int add = boff[blockIdx.x];
  for (int w = 0; w < wid; ++w) add += ws[w];
  int excl = incl - v + add;
  if (i < NNODES) { row_ptr[i] = excl; cursor[i] = excl; }
  if (i == 0) row_ptr[NNODES] = NEDGES;
}

__global__ __launch_bounds__(256) void fill_k(
    const int* __restrict__ src, const int* __restrict__ dst,
    int* __restrict__ cursor, int* __restrict__ esrc) {
  int e = blockIdx.x * 256 + threadIdx.x;
  if (e >= NEDGES) return;
  int p = atomicAdd(&cursor[dst[e]], 1);
  esrc[p] = src[e];
}

// ---------------- gather aggregation: one wave per node, bf16 out ----------------
__global__ __launch_bounds__(256) void agg_gather_k(
    const float* __restrict__ x, const int* __restrict__ row_ptr,
    const int* __restrict__ esrc, unsigned short* __restrict__ aggb) {
  int node = blockIdx.x * 4 + (threadIdx.x >> 6);
  int lane = threadIdx.x & 63;
  if (node >= NPAD) return;
  float4 acc0 = {0,0,0,0}, acc1 = {0,0,0,0}, acc2 = {0,0,0,0};
  if (node < NNODES) {
    int beg = row_ptr[node], end = row_ptr[node + 1];
    for (int i = beg; i < end; ++i) {
      const float* xr = x + (size_t)esrc[i] * ND + lane * 4;
      float4 u = *reinterpret_cast<const float4*>(xr);
      float4 v = *reinterpret_cast<const float4*>(xr + 256);
      float4 w = *reinterpret_cast<const float4*>(xr + 512);
      acc0.x += u.x; acc0.y += u.y; acc0.z += u.z; acc0.w += u.w;
      acc1.x += v.x; acc1.y += v.y; acc1.z += v.z; acc1.w += v.w;
      acc2.x += w.x; acc2.y += w.y; acc2.z += w.z; acc2.w += w.w;
    }
  }
  size_t ob = (size_t)node * ND + lane * 4;
  ushort4 o0 = { f2b(acc0.x), f2b(acc0.y), f2b(acc0.z), f2b(acc0.w) };
  ushort4 o1 = { f2b(acc1.x), f2b(acc1.y), f2b(acc1.z), f2b(acc1.w) };
  ushort4 o2 = { f2b(acc2.x), f2b(acc2.y), f2b(acc2.z), f2b(acc2.w) };
  *reinterpret_cast<ushort4*>(aggb + ob)       = o0;
  *reinterpret_cast<ushort4*>(aggb + ob + 256) = o1;
  *reinterpret_cast<ushort4*>(aggb + ob + 512) = o2;
}

// ---------------- bf16 GEMM, C = A[M,K] x Bt[N,K]^T ----------------
__global__ __launch_bounds__(256) void gemm_bt_k(
    const unsigned short* __restrict__ A,
    const unsigned short* __restrict__ Bt,
    const float* __restrict__ bias,
    unsigned short* __restrict__ outb,
    int epi) {
  __shared__ __align__(16) unsigned short lA[128 * 32];
  __shared__ __align__(16) unsigned short lB[128 * 32];
  const int tid = threadIdx.x;
  const int lane = tid & 63;
  const int wid = tid >> 6;
  const int brow = blockIdx.x / 6;
  const int bcol = blockIdx.x % 6;
  const int wr = wid >> 1, wc = wid & 1;

  f32x4 acc[4][4] = {};
  const int lr = lane & 15;
  const int ks = (lane >> 4) * 8;

  for (int k0 = 0; k0 < ND; k0 += 32) {
#pragma unroll
    for (int it = 0; it < 2; ++it) {
      int lid = it * 256 + tid;
      int r = lid >> 2;
      int c = (lid & 3) * 8;
      const unsigned short* ga = A + (size_t)(brow * 128 + r) * ND + k0 + c;
      const unsigned short* gb = Bt + (size_t)(bcol * 128 + r) * ND + k0 + c;
      unsigned short* la = &lA[(size_t)(it * 256 + wid * 64) * 8];
      unsigned short* lb = &lB[(size_t)(it * 256 + wid * 64) * 8];
      __builtin_amdgcn_global_load_lds(
          (const __attribute__((address_space(1))) char*)ga,
          (__attribute__((address_space(3))) char*)la, 16, 0, 0);
      __builtin_amdgcn_global_load_lds(
          (const __attribute__((address_space(1))) char*)gb,
          (__attribute__((address_space(3))) char*)lb, 16, 0, 0);
    }
    __syncthreads();
    bf16x8 a[4], b[4];
#pragma unroll
    for (int mi = 0; mi < 4; ++mi)
      a[mi] = *reinterpret_cast<const bf16x8*>(&lA[(wr * 64 + mi * 16 + lr) * 32 + ks]);
#pragma unroll
    for (int ni = 0; ni < 4; ++ni)
      b[ni] = *reinterpret_cast<const bf16x8*>(&lB[(wc * 64 + ni * 16 + lr) * 32 + ks]);
#pragma unroll
    for (int mi = 0; mi < 4; ++mi)
#pragma unroll
      for (int ni = 0; ni < 4; ++ni)
        acc[mi][ni] = __builtin_amdgcn_mfma_f32_16x16x32_bf16(a[mi], b[ni], acc[mi][ni], 0, 0, 0);
    __syncthreads();
  }

#pragma unroll
  for (int ni = 0; ni < 4; ++ni) {
    int col = bcol * 128 + wc * 64 + ni * 16 + lr;
    float bj = bias[col];
#pragma unroll
    for (int mi = 0; mi < 4; ++mi) {
      int row0 = brow * 128 + wr * 64 + mi * 16 + (lane >> 4) * 4;
#pragma unroll
      for (int r = 0; r < 4; ++r) {
        float v = acc[mi][ni][r] + bj;
        if (epi == 0) v = fmaxf(v, 0.f);
        else          v = 1.f / (1.f + __expf(-v));
        outb[(size_t)(row0 + r) * ND + col] = f2b(v);
      }
    }
  }
}

// ---------------- gate combine + LayerNorm ----------------
__global__ __launch_bounds__(256) void combine_ln_k(
    const unsigned short* __restrict__ gate, const unsigned short* __restrict__ xgcn,
    const float* __restrict__ xin, const float* __restrict__ gamma,
    const float* __restrict__ beta, float* __restrict__ out) {
  int row = blockIdx.x;
  int tid = threadIdx.x;
  int lane = tid & 63, wid = tid >> 6;
  size_t base = (size_t)row * ND;
  float v[3];
  float s = 0.f, s2 = 0.f;
#pragma unroll
  for (int i = 0; i < 3; ++i) {
    int c = tid + i * 256;
    float g  = b2f(gate[base + c]);
    float xg = b2f(xgcn[base + c]);
    float xo = xin[base + c];
    float val = g * xg + (1.f - g) * xo;
    v[i] = val; s += val; s2 += val * val;
  }
#pragma unroll
  for (int o = 1; o < 64; o <<= 1) { s += __shfl_xor(s, o); s2 += __shfl_xor(s2, o); }
  __shared__ float red[2][4];
  if (lane == 0) { red[0][wid] = s; red[1][wid] = s2; }
  __syncthreads();
  s  = red[0][0] + red[0][1] + red[0][2] + red[0][3];
  s2 = red[1][0] + red[1][1] + red[1][2] + red[1][3];
  float mu  = s * (1.f / ND);
  float var = s2 * (1.f / ND) - mu * mu;
  float inv = rsqrtf(var + 1e-5f);
#pragma unroll
  for (int i = 0; i < 3; ++i) {
    int c = tid + i * 256;
    out[base + c] = (v[i] - mu) * inv * gamma[c] + beta[c];
  }
}

// ---------------- launch ----------------
extern "C" void kernel_launch(void* const* d_in, const int* in_sizes, int n_in,
                              void* d_out, int out_size, void* d_ws, size_t ws_size,
                              hipStream_t stream) {
  const float* token  = (const float*)d_in[0];
  const int*   eidx   = (const int*)d_in[1];
  const float* aspect = (const float*)d_in[2];
  const float* gcn_w  = (const float*)d_in[3];
  const float* gcn_b  = (const float*)d_in[4];
  const float* gate_w = (const float*)d_in[5];
  const float* gate_b = (const float*)d_in[6];
  const float* ln_g   = (const float*)d_in[7];
  const float* ln_b   = (const float*)d_in[8];
  float* out = (float*)d_out;

  const int* src = eidx;
  const int* dst = eidx + NEDGES;

  char* ws = (char*)d_ws;
  size_t off = 0;
  unsigned short* aggb  = (unsigned short*)(ws + off); off += (size_t)NPAD * ND * 2;
  unsigned short* xgcn  = (unsigned short*)(ws + off); off += (size_t)NPAD * ND * 2;
  unsigned short* gateb = (unsigned short*)(ws + off); off += (size_t)NPAD * ND * 2;
  unsigned short* wt0   = (unsigned short*)(ws + off); off += (size_t)ND * ND * 2;
  unsigned short* wt1   = (unsigned short*)(ws + off); off += (size_t)ND * ND * 2;
  unsigned short* gwt   = (unsigned short*)(ws + off); off += (size_t)ND * ND * 2;
  float* aproj  = (float*)(ws + off); off += ND * 4;
  int* cnt      = (int*)(ws + off);   off += (size_t)NNODES * 4;
  int* row_ptr  = (int*)(ws + off);   off += (size_t)(NNODES + 1) * 4;
  int* cursor   = (int*)(ws + off);   off += (size_t)NNODES * 4;
  int* esrc     = (int*)(ws + off);   off += (size_t)NEDGES * 4;
  int* bsum     = (int*)(ws + off);   off += NSB * 4;
  int* boff     = (int*)(ws + off);   off += NSB * 4;

  // weight prep (once per launch)
  hipLaunchKernelGGL(prep_wt_k, dim3((3 * ND * ND) / 256), dim3(256), 0, stream,
                     gcn_w, gate_w, wt0, wt1, gwt);
  hipLaunchKernelGGL(prep_aspect_k, dim3(3), dim3(256), 0, stream,
                     aspect, gate_w, gate_b, aproj);

  // CSR build (once per launch; shared by both layers)
  hipMemsetAsync(cnt, 0, (size_t)NNODES * 4, stream);
  hipLaunchKernelGGL(hist_k, dim3((NEDGES + 255) / 256), dim3(256), 0, stream, dst, cnt);
  hipLaunchKernelGGL(scan1_k, dim3(NSB), dim3(256), 0, stream, cnt, bsum);
  hipLaunchKernelGGL(scan2_k, dim3(1), dim3(256), 0, stream, bsum, boff);
  hipLaunchKernelGGL(scan3_k, dim3(NSB), dim3(256), 0, stream, cnt, boff, row_ptr, cursor);
  hipLaunchKernelGGL(fill_k, dim3((NEDGES + 255) / 256), dim3(256), 0, stream,
                     src, dst, cursor, esrc);

  for (int l = 0; l < 2; ++l) {
    const float* xin = (l == 0) ? token : out;
    hipLaunchKernelGGL(agg_gather_k, dim3(NPAD / 4), dim3(256), 0, stream,
                       xin, row_ptr, esrc, aggb);
    hipLaunchKernelGGL(gemm_bt_k, dim3(391 * 6), dim3(256), 0, stream,
                       aggb, (l == 0) ? wt0 : wt1, gcn_b + l * ND, xgcn, 0);
    hipLaunchKernelGGL(gemm_bt_k, dim3(391 * 6), dim3(256), 0, stream,
                       xgcn, gwt, aproj, gateb, 1);
    hipLaunchKernelGGL(combine_ln_k, dim3(NNODES), dim3(256), 0, stream,
                       gateb, xgcn, xin, ln_g + l * ND, ln_b + l * ND, out);
  }
}